// Round 1
// 1159.281 us; speedup vs baseline: 1.2717x; 1.2717x over previous
//
#include <hip/hip_runtime.h>

// ---------------------------------------------------------------------------
// 2-layer hetero GraphSAGE, bipartite user<->item, H=256.
// Round 3: replace latency-bound per-MFMA global W loads with m97-structure
// MFMA GEMM: 128x128 tile, BK=32, global_load_lds(16B) staging of A and W,
// 2-barrier K-loop, XCD-aware bijective block swizzle.
//   convert x,W -> bf16
//   A_i = mean_ui(x_user_bf); A_u = mean_iu(x_item_bf)          [agg kernels]
//   h_item = relu(A_i@W1l^T + b + x_item@W1r^T)  (bf16 out)     [MFMA gemm]
//   h_user = relu(A_u@W1l^T + b + x_user@W1r^T)  (bf16 out)
//   B_i = mean_ui(h_user); B_u = mean_iu(h_item)
//   out_item = B_i@W2l^T + b + h_item@W2r^T      (fp32 out)
//   out_user = B_u@W2l^T + b + h_user@W2r^T
// ---------------------------------------------------------------------------

typedef unsigned short u16;
typedef unsigned int u32;
typedef short bf16x8 __attribute__((ext_vector_type(8)));   // 8 bf16 (4 VGPRs)
typedef float f32x4 __attribute__((ext_vector_type(4)));    // MFMA acc

constexpr int HDIM = 256;

// ---------------- bf16 helpers ----------------

__device__ __forceinline__ float lo2f(u32 v) { union { u32 i; float f; } x; x.i = v << 16; return x.f; }
__device__ __forceinline__ float hi2f(u32 v) { union { u32 i; float f; } x; x.i = v & 0xffff0000u; return x.f; }
__device__ __forceinline__ float bf2f(u16 v) { union { u32 i; float f; } x; x.i = ((u32)v) << 16; return x.f; }
__device__ __forceinline__ u16 f2bf(float f) {  // RNE
    union { float f; u32 i; } x; x.f = f;
    return (u16)((x.i + 0x7fffu + ((x.i >> 16) & 1u)) >> 16);
}
__device__ __forceinline__ u32 pack2(float a, float b) {
    return (u32)f2bf(a) | ((u32)f2bf(b) << 16);
}

__device__ __forceinline__ void gload16(const void* g, void* l) {
    __builtin_amdgcn_global_load_lds(
        (const __attribute__((address_space(1))) unsigned int*)g,
        (__attribute__((address_space(3))) unsigned int*)l, 16, 0, 0);
}

// ---------------- CSR build (unchanged) ----------------

__global__ void hist_kernel(const int* __restrict__ dst, int n, int* __restrict__ cnt) {
    int i = blockIdx.x * 256 + threadIdx.x;
    if (i < n) atomicAdd(&cnt[dst[i]], 1);
}

__global__ void block_reduce_kernel(const int* __restrict__ cnt, int n, int* __restrict__ sums) {
    __shared__ int sdata[256];
    int b = blockIdx.x, t = threadIdx.x;
    int v = 0;
#pragma unroll
    for (int j = 0; j < 4; j++) {
        int idx = b * 1024 + j * 256 + t;
        if (idx < n) v += cnt[idx];
    }
    sdata[t] = v;
    __syncthreads();
    for (int s = 128; s > 0; s >>= 1) {
        if (t < s) sdata[t] += sdata[t + s];
        __syncthreads();
    }
    if (t == 0) sums[b] = sdata[0];
}

__global__ void scan_sums_kernel(const int* __restrict__ sums, int* __restrict__ offs, int B) {
    if (blockIdx.x == 0 && threadIdx.x == 0) {
        int a = 0;
        for (int i = 0; i < B; i++) { offs[i] = a; a += sums[i]; }
    }
}

__global__ void block_scan_write_kernel(const int* cnt, int n, const int* __restrict__ offs,
                                        int* __restrict__ rp, int* cursor, int total) {
    __shared__ int sdata[1024];
    int b = blockIdx.x, t = threadIdx.x;
    int idx = b * 1024 + t;
    int v = (idx < n) ? cnt[idx] : 0;
    sdata[t] = v;
    __syncthreads();
    for (int s = 1; s < 1024; s <<= 1) {
        int x = (t >= s) ? sdata[t - s] : 0;
        __syncthreads();
        sdata[t] += x;
        __syncthreads();
    }
    if (idx < n) {
        int excl = sdata[t] - v + offs[b];
        rp[idx] = excl;
        cursor[idx] = excl;
    }
    if (b == 0 && t == 0) rp[n] = total;
}

__global__ void fill_kernel(const int* __restrict__ src, const int* __restrict__ dst, int n,
                            int* cursor, int* __restrict__ col) {
    int i = blockIdx.x * 256 + threadIdx.x;
    if (i < n) {
        int p = atomicAdd(&cursor[dst[i]], 1);
        col[p] = src[i];
    }
}

// ---------------- fp32 -> bf16 convert (n must be multiple of 4) ----------------

__global__ void f32_to_bf16_kernel(const float* __restrict__ in, u16* __restrict__ out, int n4) {
    int i = blockIdx.x * 256 + threadIdx.x;
    if (i < n4) {
        float4 v = ((const float4*)in)[i];
        ((uint2*)out)[i] = make_uint2(pack2(v.x, v.y), pack2(v.z, v.w));
    }
}

// ---------------- mean aggregation: 1 wave per dst row (unchanged) ----------------

template <int F>
__global__ __launch_bounds__(256) void agg_mean(const u16* __restrict__ src,
                                                const int* __restrict__ rp,
                                                const int* __restrict__ col,
                                                u16* __restrict__ out, int n_dst) {
    constexpr int VE = F / 64;  // bf16 per lane: 4 / 2 / 1
    const int lane = threadIdx.x & 63;
    const int d = blockIdx.x * 4 + (threadIdx.x >> 6);
    if (d >= n_dst) return;
    const int e0 = rp[d], e1 = rp[d + 1];
    float a0 = 0.f, a1 = 0.f, a2 = 0.f, a3 = 0.f;
    const size_t lo = (size_t)lane * VE;

    auto add = [&](int c) {
        const u16* p = src + (size_t)c * F + lo;
        if (VE == 4) {
            uint2 v = *(const uint2*)p;
            a0 += lo2f(v.x); a1 += hi2f(v.x); a2 += lo2f(v.y); a3 += hi2f(v.y);
        } else if (VE == 2) {
            u32 v = *(const u32*)p;
            a0 += lo2f(v); a1 += hi2f(v);
        } else {
            a0 += bf2f(*p);
        }
    };

    int e = e0;
    for (; e + 4 <= e1; e += 4) {
        int c0 = col[e], c1 = col[e + 1], c2 = col[e + 2], c3 = col[e + 3];
        add(c0); add(c1); add(c2); add(c3);
    }
    for (; e < e1; e++) add(col[e]);

    int deg = e1 - e0;
    float inv = (deg > 0) ? 1.f / (float)deg : 0.f;
    a0 *= inv; a1 *= inv; a2 *= inv; a3 *= inv;

    u16* q = out + (size_t)d * F + lo;
    if (VE == 4)      ((uint2*)q)[0] = make_uint2(pack2(a0, a1), pack2(a2, a3));
    else if (VE == 2) ((u32*)q)[0] = pack2(a0, a1);
    else              *q = f2bf(a0);
}

// ---------------- MFMA GEMM, m97 structure ----------------
// out[Mx256] = [A | X] @ [WA | WB]^T + bias   (K = KA + KB, W row-major [256][K*])
// Block: 256 threads = 4 waves, output tile 128 rows x 128 cols (2 N-blocks).
// Wave (wr,wc) = (wid>>1, wid&1) owns 64x64: acc[4][4] f32x4.
// Per K-step (BK=32): stage A-chunk [128x32] + W-chunk [128x32] into LDS via
// global_load_lds width 16 (linear dest, wave-uniform base + lane*16);
// contiguous 1KB ds_read_b128 fragment loads; 16 MFMA per wave.
// mfma_f32_16x16x32_bf16 layouts (HW-verified):
//   A: lane holds A[m=lane&15][k=ql*8+j]
//   B: lane holds B[k=ql*8+j][n=lane&15] = W[n][k]
//   C/D: col=lane&15, row=ql*4+reg

template <int KA, int KB, bool RELU, bool OUT_BF16>
__global__ __launch_bounds__(256, 3) void gemm_tile(const u16* __restrict__ A,
                                                    const u16* __restrict__ X,
                                                    const u16* __restrict__ WA,
                                                    const u16* __restrict__ WB,
                                                    const float* __restrict__ bias,
                                                    float* __restrict__ outF,
                                                    u16* __restrict__ outB, int M) {
    constexpr int KT = KA + KB;
    constexpr int NKT = KT / 32;
    __shared__ __align__(16) u16 Al[128 * 32];   // 8 KB, rows of 32 bf16 (64B)
    __shared__ __align__(16) u16 Wl[128 * 32];   // 8 KB

    // XCD-aware bijective swizzle (m204): hw block b -> logical tile, contiguous per XCD
    const int nwg = gridDim.x;
    const int b = blockIdx.x;
    const int q = nwg >> 3, r = nwg & 7;
    const int xcd = b & 7, within = b >> 3;
    const int logical = (xcd < r ? xcd * (q + 1) : r * (q + 1) + (xcd - r) * q) + within;
    const int mb = logical >> 1;     // n-fastest: the 2 N-halves of an M-tile stay adjacent
    const int nb = logical & 1;
    const int row0 = mb * 128;
    const int ncol0 = nb * 128;

    const int tid = threadIdx.x;
    const int lane = tid & 63;
    const int wid = tid >> 6;
    const int wr = wid >> 1;          // wave row (0..1) -> rows wr*64..+64
    const int wc = wid & 1;           // wave col (0..1) -> cols wc*64..+64
    const int ml = lane & 15;
    const int ql = lane >> 4;
    const int lrow4 = lane >> 2;      // staging: row within 16-row segment
    const int lcol8 = (lane & 3) * 8; // staging: bf16 col offset (16B granules)

    f32x4 acc[4][4];
#pragma unroll
    for (int m = 0; m < 4; m++)
#pragma unroll
        for (int n = 0; n < 4; n++) acc[m][n] = {0.f, 0.f, 0.f, 0.f};

    const int s0 = wid * 2;  // this wave's two 16-row segments (of 8)

#pragma unroll
    for (int kt = 0; kt < NKT; ++kt) {
        const int kk = kt * 32;
        // ---- stage A-chunk rows [row0, row0+128) x k [kk, kk+32) ----
#pragma unroll
        for (int j = 0; j < 2; ++j) {
            const int s = s0 + j;
            int gr = row0 + s * 16 + lrow4;
            gr = (gr < M) ? gr : (M - 1);  // clamp: garbage rows never written out
            const u16* gp = (kk < KA) ? (A + (size_t)gr * KA + (kk + lcol8))
                                      : (X + (size_t)gr * KB + (kk - KA + lcol8));
            gload16(gp, &Al[s * 512]);     // dest = base + lane*16B (linear)
        }
        // ---- stage W-chunk rows [ncol0, ncol0+128) x k [kk, kk+32) ----
#pragma unroll
        for (int j = 0; j < 2; ++j) {
            const int s = s0 + j;
            const int gn = ncol0 + s * 16 + lrow4;   // always < 256, no guard
            const u16* gp = (kk < KA) ? (WA + (size_t)gn * KA + (kk + lcol8))
                                      : (WB + (size_t)gn * KB + (kk - KA + lcol8));
            gload16(gp, &Wl[s * 512]);
        }
        __syncthreads();  // drains vmcnt: LDS chunk ready

        bf16x8 af[4], wf[4];
#pragma unroll
        for (int m = 0; m < 4; m++)
            af[m] = *(const bf16x8*)&Al[(wr * 64 + m * 16 + ml) * 32 + ql * 8];
#pragma unroll
        for (int n = 0; n < 4; n++)
            wf[n] = *(const bf16x8*)&Wl[(wc * 64 + n * 16 + ml) * 32 + ql * 8];
#pragma unroll
        for (int m = 0; m < 4; m++)
#pragma unroll
            for (int n = 0; n < 4; n++)
                acc[m][n] = __builtin_amdgcn_mfma_f32_16x16x32_bf16(af[m], wf[n], acc[m][n], 0, 0, 0);
        __syncthreads();  // all reads done before next stage overwrites
    }

    // ---- epilogue ----
#pragma unroll
    for (int n = 0; n < 4; n++) {
        const int gcol = ncol0 + wc * 64 + n * 16 + ml;
        const float bv = bias[gcol];
#pragma unroll
        for (int m = 0; m < 4; m++) {
            const int gr0 = row0 + wr * 64 + m * 16 + ql * 4;
#pragma unroll
            for (int rr = 0; rr < 4; rr++) {
                const int grow = gr0 + rr;
                if (grow >= M) continue;
                float v = acc[m][n][rr] + bv;
                if (RELU) v = fmaxf(v, 0.f);
                if (OUT_BF16) outB[(size_t)grow * HDIM + gcol] = f2bf(v);
                else          outF[(size_t)grow * HDIM + gcol] = v;
            }
        }
    }
}

// ---------------- host ----------------

extern "C" void kernel_launch(void* const* d_in, const int* in_sizes, int n_in,
                              void* d_out, int out_size, void* d_ws, size_t ws_size,
                              hipStream_t stream) {
    const float* x_user = (const float*)d_in[0];
    const float* x_item = (const float*)d_in[1];
    const int* eui_src = (const int*)d_in[2];
    const int* eui_dst = (const int*)d_in[3];
    const int* eiu_src = (const int*)d_in[4];
    const int* eiu_dst = (const int*)d_in[5];
    const float* W1l_ui = (const float*)d_in[6];
    const float* b1_ui  = (const float*)d_in[7];
    const float* W1r_ui = (const float*)d_in[8];
    const float* W1l_iu = (const float*)d_in[9];
    const float* b1_iu  = (const float*)d_in[10];
    const float* W1r_iu = (const float*)d_in[11];
    const float* W2l_ui = (const float*)d_in[12];
    const float* b2_ui  = (const float*)d_in[13];
    const float* W2r_ui = (const float*)d_in[14];
    const float* W2l_iu = (const float*)d_in[15];
    const float* b2_iu  = (const float*)d_in[16];
    const float* W2r_iu = (const float*)d_in[17];

    const int DU = 128, DI = 64;
    const int NU = in_sizes[0] / DU;   // 100000
    const int NI = in_sizes[1] / DI;   // 50000
    const int E  = in_sizes[2];        // 1600000

    // ---- carve workspace (256B aligned) ----
    char* base = (char*)d_ws;
    size_t off = 0;
    auto carve = [&](size_t bytes) -> char* {
        char* p = base + off;
        off += (bytes + 255) & ~(size_t)255;
        return p;
    };
    int* cnt_i  = (int*)carve((size_t)NI * 4);
    int* cnt_u  = (int*)carve((size_t)NU * 4);
    int* rp_i   = (int*)carve((size_t)(NI + 1) * 4);
    int* rp_u   = (int*)carve((size_t)(NU + 1) * 4);
    int* col_ui = (int*)carve((size_t)E * 4);
    int* col_iu = (int*)carve((size_t)E * 4);
    int* bsum   = (int*)carve(1024 * 4);
    int* boff   = (int*)carve(1024 * 4);
    // bf16 weights
    u16* W1l_ui_b = (u16*)carve((size_t)HDIM * DU * 2);
    u16* W1r_ui_b = (u16*)carve((size_t)HDIM * DI * 2);
    u16* W1l_iu_b = (u16*)carve((size_t)HDIM * DI * 2);
    u16* W1r_iu_b = (u16*)carve((size_t)HDIM * DU * 2);
    u16* W2l_ui_b = (u16*)carve((size_t)HDIM * HDIM * 2);
    u16* W2r_ui_b = (u16*)carve((size_t)HDIM * HDIM * 2);
    u16* W2l_iu_b = (u16*)carve((size_t)HDIM * HDIM * 2);
    u16* W2r_iu_b = (u16*)carve((size_t)HDIM * HDIM * 2);
    // slot1 (25.6 MB): x_user_bf, later B_i (mean of h_user, [NI x 256])
    char* slot1 = carve((size_t)NU * DU * 2);          // == NI*HDIM*2
    u16* x_user_b = (u16*)slot1;
    u16* B_i      = (u16*)slot1;
    // slotB (51.2 MB): x_item_bf + A_i + A_u, later B_u ([NU x 256])
    char* slotB = carve((size_t)NU * HDIM * 2);
    u16* x_item_b = (u16*)slotB;                               // NI*64*2  = 6.4 MB
    u16* A_i      = (u16*)(slotB + (size_t)NI * DI * 2);       // NI*128*2 = 12.8 MB
    u16* A_u      = (u16*)(slotB + (size_t)NI * DI * 2 + (size_t)NI * DU * 2);  // NU*64*2
    u16* B_u      = (u16*)slotB;
    // h buffers (persist through layer 2)
    u16* h_item_b = (u16*)carve((size_t)NI * HDIM * 2);  // 25.6 MB
    u16* h_user_b = (u16*)carve((size_t)NU * HDIM * 2);  // 51.2 MB

    float* out_user = (float*)d_out;
    float* out_item = (float*)d_out + (size_t)NU * HDIM;

    // ---- CSR build ----
    hipMemsetAsync(cnt_i, 0, (size_t)NI * 4, stream);
    hipMemsetAsync(cnt_u, 0, (size_t)NU * 4, stream);
    int egrid = (E + 255) / 256;
    hist_kernel<<<egrid, 256, 0, stream>>>(eui_dst, E, cnt_i);
    hist_kernel<<<egrid, 256, 0, stream>>>(eiu_dst, E, cnt_u);
    int Bi = (NI + 1023) / 1024, Bu = (NU + 1023) / 1024;
    block_reduce_kernel<<<Bi, 256, 0, stream>>>(cnt_i, NI, bsum);
    scan_sums_kernel<<<1, 64, 0, stream>>>(bsum, boff, Bi);
    block_scan_write_kernel<<<Bi, 1024, 0, stream>>>(cnt_i, NI, boff, rp_i, cnt_i, E);
    fill_kernel<<<egrid, 256, 0, stream>>>(eui_src, eui_dst, E, cnt_i, col_ui);
    block_reduce_kernel<<<Bu, 256, 0, stream>>>(cnt_u, NU, bsum);
    scan_sums_kernel<<<1, 64, 0, stream>>>(bsum, boff, Bu);
    block_scan_write_kernel<<<Bu, 1024, 0, stream>>>(cnt_u, NU, boff, rp_u, cnt_u, E);
    fill_kernel<<<egrid, 256, 0, stream>>>(eiu_src, eiu_dst, E, cnt_u, col_iu);

    // ---- converts ----
    auto conv = [&](const float* in, u16* outp, size_t n) {
        int n4 = (int)(n / 4);
        f32_to_bf16_kernel<<<(n4 + 255) / 256, 256, 0, stream>>>(in, outp, n4);
    };
    conv(x_user, x_user_b, (size_t)NU * DU);
    conv(x_item, x_item_b, (size_t)NI * DI);
    conv(W1l_ui, W1l_ui_b, (size_t)HDIM * DU);
    conv(W1r_ui, W1r_ui_b, (size_t)HDIM * DI);
    conv(W1l_iu, W1l_iu_b, (size_t)HDIM * DI);
    conv(W1r_iu, W1r_iu_b, (size_t)HDIM * DU);
    conv(W2l_ui, W2l_ui_b, (size_t)HDIM * HDIM);
    conv(W2r_ui, W2r_ui_b, (size_t)HDIM * HDIM);
    conv(W2l_iu, W2l_iu_b, (size_t)HDIM * HDIM);
    conv(W2r_iu, W2r_iu_b, (size_t)HDIM * HDIM);

    // ---- layer 1 ----
    agg_mean<128><<<(NI + 3) / 4, 256, 0, stream>>>(x_user_b, rp_i, col_ui, A_i, NI);
    agg_mean<64> <<<(NU + 3) / 4, 256, 0, stream>>>(x_item_b, rp_u, col_iu, A_u, NU);
    {
        int gi = ((NI + 127) / 128) * 2;
        int gu = ((NU + 127) / 128) * 2;
        gemm_tile<128, 64, true, true><<<gi, 256, 0, stream>>>(
            A_i, x_item_b, W1l_ui_b, W1r_ui_b, b1_ui, nullptr, h_item_b, NI);
        gemm_tile<64, 128, true, true><<<gu, 256, 0, stream>>>(
            A_u, x_user_b, W1l_iu_b, W1r_iu_b, b1_iu, nullptr, h_user_b, NU);
    }

    // ---- layer 2 ----  (B_i overwrites x_user_b; B_u overwrites x_item/A_i/A_u: all dead)
    agg_mean<256><<<(NI + 3) / 4, 256, 0, stream>>>(h_user_b, rp_i, col_ui, B_i, NI);
    agg_mean<256><<<(NU + 3) / 4, 256, 0, stream>>>(h_item_b, rp_u, col_iu, B_u, NU);
    {
        int gi = ((NI + 127) / 128) * 2;
        int gu = ((NU + 127) / 128) * 2;
        gemm_tile<256, 256, false, false><<<gi, 256, 0, stream>>>(
            B_i, h_item_b, W2l_ui_b, W2r_ui_b, b2_ui, out_item, nullptr, NI);
        gemm_tile<256, 256, false, false><<<gu, 256, 0, stream>>>(
            B_u, h_user_b, W2l_iu_b, W2r_iu_b, b2_iu, out_user, nullptr, NU);
    }
}

// Round 2
// 988.717 us; speedup vs baseline: 1.4911x; 1.1725x over previous
//
#include <hip/hip_runtime.h>

// ---------------------------------------------------------------------------
// 2-layer hetero GraphSAGE, bipartite user<->item, H=256.
// Round 4: bucketed two-pass CSR fill. Old fill_kernel scattered 4B stores
// across a 6.4MB array from all XCDs -> 16x write amplification (100MB HBM
// writes, 130us each). New scheme: LDS-binned coarse scatter into per-bucket
// runs (one block = one XCD per run), then block-per-bucket fine fill with
// LDS cursors (writes confined to the block's ~16KB col region).
// GEMM (m97 structure) and aggregation unchanged from round 3.
// ---------------------------------------------------------------------------

typedef unsigned short u16;
typedef unsigned int u32;
typedef short bf16x8 __attribute__((ext_vector_type(8)));   // 8 bf16 (4 VGPRs)
typedef float f32x4 __attribute__((ext_vector_type(4)));    // MFMA acc

constexpr int HDIM = 256;
constexpr int RB = 128;       // dst rows per bucket (b = dst >> 7)
constexpr int MAXB = 784;     // max buckets: ceil(100000/128) = 782
constexpr int CHUNK = 4096;   // edges per binned_scatter block

// ---------------- bf16 helpers ----------------

__device__ __forceinline__ float lo2f(u32 v) { union { u32 i; float f; } x; x.i = v << 16; return x.f; }
__device__ __forceinline__ float hi2f(u32 v) { union { u32 i; float f; } x; x.i = v & 0xffff0000u; return x.f; }
__device__ __forceinline__ float bf2f(u16 v) { union { u32 i; float f; } x; x.i = ((u32)v) << 16; return x.f; }
__device__ __forceinline__ u16 f2bf(float f) {  // RNE
    union { float f; u32 i; } x; x.f = f;
    return (u16)((x.i + 0x7fffu + ((x.i >> 16) & 1u)) >> 16);
}
__device__ __forceinline__ u32 pack2(float a, float b) {
    return (u32)f2bf(a) | ((u32)f2bf(b) << 16);
}

__device__ __forceinline__ void gload16(const void* g, void* l) {
    __builtin_amdgcn_global_load_lds(
        (const __attribute__((address_space(1))) unsigned int*)g,
        (__attribute__((address_space(3))) unsigned int*)l, 16, 0, 0);
}

// ---------------- CSR build ----------------

__global__ void hist_kernel(const int* __restrict__ dst, int n, int* __restrict__ cnt) {
    int i = blockIdx.x * 256 + threadIdx.x;
    if (i < n) atomicAdd(&cnt[dst[i]], 1);
}

__global__ void block_reduce_kernel(const int* __restrict__ cnt, int n, int* __restrict__ sums) {
    __shared__ int sdata[256];
    int b = blockIdx.x, t = threadIdx.x;
    int v = 0;
#pragma unroll
    for (int j = 0; j < 4; j++) {
        int idx = b * 1024 + j * 256 + t;
        if (idx < n) v += cnt[idx];
    }
    sdata[t] = v;
    __syncthreads();
    for (int s = 128; s > 0; s >>= 1) {
        if (t < s) sdata[t] += sdata[t + s];
        __syncthreads();
    }
    if (t == 0) sums[b] = sdata[0];
}

__global__ void scan_sums_kernel(const int* __restrict__ sums, int* __restrict__ offs, int B) {
    if (blockIdx.x == 0 && threadIdx.x == 0) {
        int a = 0;
        for (int i = 0; i < B; i++) { offs[i] = a; a += sums[i]; }
    }
}

__global__ void block_scan_write_kernel(const int* cnt, int n, const int* __restrict__ offs,
                                        int* __restrict__ rp, int* cursor, int total) {
    __shared__ int sdata[1024];
    int b = blockIdx.x, t = threadIdx.x;
    int idx = b * 1024 + t;
    int v = (idx < n) ? cnt[idx] : 0;
    sdata[t] = v;
    __syncthreads();
    for (int s = 1; s < 1024; s <<= 1) {
        int x = (t >= s) ? sdata[t - s] : 0;
        __syncthreads();
        sdata[t] += x;
        __syncthreads();
    }
    if (idx < n) {
        int excl = sdata[t] - v + offs[b];
        rp[idx] = excl;
        cursor[idx] = excl;
    }
    if (b == 0 && t == 0) rp[n] = total;
}

// bcur[b] = rp[b*RB]  (bucket write cursor for coarse scatter)
__global__ void bucket_init_kernel(const int* __restrict__ rp, int n, int nb,
                                   int* __restrict__ bcur) {
    int b = blockIdx.x * 256 + threadIdx.x;
    if (b < nb) {
        int row = b * RB;
        bcur[b] = rp[row < n ? row : n];
    }
}

// Pass 1: bin edges by dst-bucket. Each block claims per-bucket runs with ONE
// global atomic per nonzero bucket, then writes (src,dst) pairs into its runs.
// All writes to a run come from one block (one XCD) -> L2 line merge works.
__global__ __launch_bounds__(256) void binned_scatter(const int* __restrict__ src,
                                                      const int* __restrict__ dst, int E,
                                                      int nb, int* __restrict__ bcur,
                                                      uint2* __restrict__ pairs) {
    __shared__ int lcnt[MAXB];
    __shared__ int lbase[MAXB];
    const int t = threadIdx.x;
    const int chunk = blockIdx.x * CHUNK;

    for (int b = t; b < nb; b += 256) lcnt[b] = 0;
    __syncthreads();

    u32 ss[CHUNK / 256], dd[CHUNK / 256];
#pragma unroll
    for (int j = 0; j < CHUNK / 256; j++) {
        int i = chunk + j * 256 + t;
        if (i < E) {
            ss[j] = (u32)src[i];
            dd[j] = (u32)dst[i];
            atomicAdd(&lcnt[dd[j] >> 7], 1);
        } else {
            ss[j] = 0; dd[j] = 0;
        }
    }
    __syncthreads();

    for (int b = t; b < nb; b += 256) {
        int c = lcnt[b];
        lbase[b] = (c > 0) ? atomicAdd(&bcur[b], c) : 0;
    }
    __syncthreads();
    for (int b = t; b < nb; b += 256) lcnt[b] = 0;  // reuse as rank counters
    __syncthreads();

#pragma unroll
    for (int j = 0; j < CHUNK / 256; j++) {
        int i = chunk + j * 256 + t;
        if (i < E) {
            int b = (int)(dd[j] >> 7);
            int r = atomicAdd(&lcnt[b], 1);
            pairs[(size_t)lbase[b] + r] = make_uint2(ss[j], dd[j]);
        }
    }
}

// Pass 2: one block per bucket. Cursors live in LDS; col writes confined to
// this block's contiguous region of col -> no write amplification.
__global__ __launch_bounds__(256) void bucket_fill(const uint2* __restrict__ pairs,
                                                   const int* __restrict__ rp, int n,
                                                   int* __restrict__ col) {
    __shared__ int lcur[RB];
    const int b = blockIdx.x;
    const int r0 = b * RB;
    const int rend = (r0 + RB < n) ? r0 + RB : n;
    const int t = threadIdx.x;
    if (t < RB) {
        int row = r0 + t;
        lcur[t] = (row < rend) ? rp[row] : 0;
    }
    __syncthreads();
    const int e0 = rp[r0];
    const int e1 = rp[rend];
    for (int j = e0 + t; j < e1; j += 256) {
        uint2 e = pairs[j];
        int p = atomicAdd(&lcur[e.y - (u32)r0], 1);
        col[p] = (int)e.x;
    }
}

// ---------------- fp32 -> bf16 convert (n must be multiple of 4) ----------------

__global__ void f32_to_bf16_kernel(const float* __restrict__ in, u16* __restrict__ out, int n4) {
    int i = blockIdx.x * 256 + threadIdx.x;
    if (i < n4) {
        float4 v = ((const float4*)in)[i];
        ((uint2*)out)[i] = make_uint2(pack2(v.x, v.y), pack2(v.z, v.w));
    }
}

// ---------------- mean aggregation: 1 wave per dst row (unchanged) ----------------

template <int F>
__global__ __launch_bounds__(256) void agg_mean(const u16* __restrict__ src,
                                                const int* __restrict__ rp,
                                                const int* __restrict__ col,
                                                u16* __restrict__ out, int n_dst) {
    constexpr int VE = F / 64;  // bf16 per lane: 4 / 2 / 1
    const int lane = threadIdx.x & 63;
    const int d = blockIdx.x * 4 + (threadIdx.x >> 6);
    if (d >= n_dst) return;
    const int e0 = rp[d], e1 = rp[d + 1];
    float a0 = 0.f, a1 = 0.f, a2 = 0.f, a3 = 0.f;
    const size_t lo = (size_t)lane * VE;

    auto add = [&](int c) {
        const u16* p = src + (size_t)c * F + lo;
        if (VE == 4) {
            uint2 v = *(const uint2*)p;
            a0 += lo2f(v.x); a1 += hi2f(v.x); a2 += lo2f(v.y); a3 += hi2f(v.y);
        } else if (VE == 2) {
            u32 v = *(const u32*)p;
            a0 += lo2f(v); a1 += hi2f(v);
        } else {
            a0 += bf2f(*p);
        }
    };

    int e = e0;
    for (; e + 4 <= e1; e += 4) {
        int c0 = col[e], c1 = col[e + 1], c2 = col[e + 2], c3 = col[e + 3];
        add(c0); add(c1); add(c2); add(c3);
    }
    for (; e < e1; e++) add(col[e]);

    int deg = e1 - e0;
    float inv = (deg > 0) ? 1.f / (float)deg : 0.f;
    a0 *= inv; a1 *= inv; a2 *= inv; a3 *= inv;

    u16* q = out + (size_t)d * F + lo;
    if (VE == 4)      ((uint2*)q)[0] = make_uint2(pack2(a0, a1), pack2(a2, a3));
    else if (VE == 2) ((u32*)q)[0] = pack2(a0, a1);
    else              *q = f2bf(a0);
}

// ---------------- MFMA GEMM, m97 structure (unchanged from round 3) ----------------
// out[Mx256] = [A | X] @ [WA | WB]^T + bias   (K = KA + KB, W row-major [256][K*])
// Block: 256 threads = 4 waves, output tile 128 rows x 128 cols (2 N-blocks).
// Wave (wr,wc) = (wid>>1, wid&1) owns 64x64: acc[4][4] f32x4.
// mfma_f32_16x16x32_bf16 layouts (HW-verified):
//   A: lane holds A[m=lane&15][k=ql*8+j]
//   B: lane holds B[k=ql*8+j][n=lane&15] = W[n][k]
//   C/D: col=lane&15, row=ql*4+reg

template <int KA, int KB, bool RELU, bool OUT_BF16>
__global__ __launch_bounds__(256, 3) void gemm_tile(const u16* __restrict__ A,
                                                    const u16* __restrict__ X,
                                                    const u16* __restrict__ WA,
                                                    const u16* __restrict__ WB,
                                                    const float* __restrict__ bias,
                                                    float* __restrict__ outF,
                                                    u16* __restrict__ outB, int M) {
    constexpr int KT = KA + KB;
    constexpr int NKT = KT / 32;
    __shared__ __align__(16) u16 Al[128 * 32];   // 8 KB, rows of 32 bf16 (64B)
    __shared__ __align__(16) u16 Wl[128 * 32];   // 8 KB

    // XCD-aware bijective swizzle (m204)
    const int nwg = gridDim.x;
    const int b = blockIdx.x;
    const int q = nwg >> 3, r = nwg & 7;
    const int xcd = b & 7, within = b >> 3;
    const int logical = (xcd < r ? xcd * (q + 1) : r * (q + 1) + (xcd - r) * q) + within;
    const int mb = logical >> 1;
    const int nb = logical & 1;
    const int row0 = mb * 128;
    const int ncol0 = nb * 128;

    const int tid = threadIdx.x;
    const int lane = tid & 63;
    const int wid = tid >> 6;
    const int wr = wid >> 1;
    const int wc = wid & 1;
    const int ml = lane & 15;
    const int ql = lane >> 4;
    const int lrow4 = lane >> 2;
    const int lcol8 = (lane & 3) * 8;

    f32x4 acc[4][4];
#pragma unroll
    for (int m = 0; m < 4; m++)
#pragma unroll
        for (int n = 0; n < 4; n++) acc[m][n] = {0.f, 0.f, 0.f, 0.f};

    const int s0 = wid * 2;

#pragma unroll
    for (int kt = 0; kt < NKT; ++kt) {
        const int kk = kt * 32;
#pragma unroll
        for (int j = 0; j < 2; ++j) {
            const int s = s0 + j;
            int gr = row0 + s * 16 + lrow4;
            gr = (gr < M) ? gr : (M - 1);
            const u16* gp = (kk < KA) ? (A + (size_t)gr * KA + (kk + lcol8))
                                      : (X + (size_t)gr * KB + (kk - KA + lcol8));
            gload16(gp, &Al[s * 512]);
        }
#pragma unroll
        for (int j = 0; j < 2; ++j) {
            const int s = s0 + j;
            const int gn = ncol0 + s * 16 + lrow4;
            const u16* gp = (kk < KA) ? (WA + (size_t)gn * KA + (kk + lcol8))
                                      : (WB + (size_t)gn * KB + (kk - KA + lcol8));
            gload16(gp, &Wl[s * 512]);
        }
        __syncthreads();

        bf16x8 af[4], wf[4];
#pragma unroll
        for (int m = 0; m < 4; m++)
            af[m] = *(const bf16x8*)&Al[(wr * 64 + m * 16 + ml) * 32 + ql * 8];
#pragma unroll
        for (int n = 0; n < 4; n++)
            wf[n] = *(const bf16x8*)&Wl[(wc * 64 + n * 16 + ml) * 32 + ql * 8];
#pragma unroll
        for (int m = 0; m < 4; m++)
#pragma unroll
            for (int n = 0; n < 4; n++)
                acc[m][n] = __builtin_amdgcn_mfma_f32_16x16x32_bf16(af[m], wf[n], acc[m][n], 0, 0, 0);
        __syncthreads();
    }

#pragma unroll
    for (int n = 0; n < 4; n++) {
        const int gcol = ncol0 + wc * 64 + n * 16 + ml;
        const float bv = bias[gcol];
#pragma unroll
        for (int m = 0; m < 4; m++) {
            const int gr0 = row0 + wr * 64 + m * 16 + ql * 4;
#pragma unroll
            for (int rr = 0; rr < 4; rr++) {
                const int grow = gr0 + rr;
                if (grow >= M) continue;
                float v = acc[m][n][rr] + bv;
                if (RELU) v = fmaxf(v, 0.f);
                if (OUT_BF16) outB[(size_t)grow * HDIM + gcol] = f2bf(v);
                else          outF[(size_t)grow * HDIM + gcol] = v;
            }
        }
    }
}

// ---------------- host ----------------

extern "C" void kernel_launch(void* const* d_in, const int* in_sizes, int n_in,
                              void* d_out, int out_size, void* d_ws, size_t ws_size,
                              hipStream_t stream) {
    const float* x_user = (const float*)d_in[0];
    const float* x_item = (const float*)d_in[1];
    const int* eui_src = (const int*)d_in[2];
    const int* eui_dst = (const int*)d_in[3];
    const int* eiu_src = (const int*)d_in[4];
    const int* eiu_dst = (const int*)d_in[5];
    const float* W1l_ui = (const float*)d_in[6];
    const float* b1_ui  = (const float*)d_in[7];
    const float* W1r_ui = (const float*)d_in[8];
    const float* W1l_iu = (const float*)d_in[9];
    const float* b1_iu  = (const float*)d_in[10];
    const float* W1r_iu = (const float*)d_in[11];
    const float* W2l_ui = (const float*)d_in[12];
    const float* b2_ui  = (const float*)d_in[13];
    const float* W2r_ui = (const float*)d_in[14];
    const float* W2l_iu = (const float*)d_in[15];
    const float* b2_iu  = (const float*)d_in[16];
    const float* W2r_iu = (const float*)d_in[17];

    const int DU = 128, DI = 64;
    const int NU = in_sizes[0] / DU;   // 100000
    const int NI = in_sizes[1] / DI;   // 50000
    const int E  = in_sizes[2];        // 1600000

    // ---- carve workspace (256B aligned) ----
    char* base = (char*)d_ws;
    size_t off = 0;
    auto carve = [&](size_t bytes) -> char* {
        char* p = base + off;
        off += (bytes + 255) & ~(size_t)255;
        return p;
    };
    int* cnt_i  = (int*)carve((size_t)NI * 4);
    int* cnt_u  = (int*)carve((size_t)NU * 4);
    int* rp_i   = (int*)carve((size_t)(NI + 1) * 4);
    int* rp_u   = (int*)carve((size_t)(NU + 1) * 4);
    int* col_ui = (int*)carve((size_t)E * 4);
    int* col_iu = (int*)carve((size_t)E * 4);
    int* bsum   = (int*)carve(1024 * 4);
    int* boff   = (int*)carve(1024 * 4);
    int* bcur_i = (int*)carve(MAXB * 4);
    int* bcur_u = (int*)carve(MAXB * 4);
    // bf16 weights
    u16* W1l_ui_b = (u16*)carve((size_t)HDIM * DU * 2);
    u16* W1r_ui_b = (u16*)carve((size_t)HDIM * DI * 2);
    u16* W1l_iu_b = (u16*)carve((size_t)HDIM * DI * 2);
    u16* W1r_iu_b = (u16*)carve((size_t)HDIM * DU * 2);
    u16* W2l_ui_b = (u16*)carve((size_t)HDIM * HDIM * 2);
    u16* W2r_ui_b = (u16*)carve((size_t)HDIM * HDIM * 2);
    u16* W2l_iu_b = (u16*)carve((size_t)HDIM * HDIM * 2);
    u16* W2r_iu_b = (u16*)carve((size_t)HDIM * HDIM * 2);
    // slot1 (25.6 MB): x_user_bf, later B_i (mean of h_user, [NI x 256])
    char* slot1 = carve((size_t)NU * DU * 2);          // == NI*HDIM*2
    u16* x_user_b = (u16*)slot1;
    u16* B_i      = (u16*)slot1;
    // slotB (51.2 MB): x_item_bf + A_i + A_u, later B_u ([NU x 256])
    char* slotB = carve((size_t)NU * HDIM * 2);
    u16* x_item_b = (u16*)slotB;                               // NI*64*2  = 6.4 MB
    u16* A_i      = (u16*)(slotB + (size_t)NI * DI * 2);       // NI*128*2 = 12.8 MB
    u16* A_u      = (u16*)(slotB + (size_t)NI * DI * 2 + (size_t)NI * DU * 2);  // NU*64*2
    u16* B_u      = (u16*)slotB;
    // h buffers (persist through layer 2)
    u16* h_item_b = (u16*)carve((size_t)NI * HDIM * 2);  // 25.6 MB
    u16* h_user_b = (u16*)carve((size_t)NU * HDIM * 2);  // 51.2 MB

    // pairs scratch (12.8 MB) aliases h_user_b: dead until layer-1 gemm (same stream)
    uint2* pairs = (uint2*)h_user_b;

    float* out_user = (float*)d_out;
    float* out_item = (float*)d_out + (size_t)NU * HDIM;

    // ---- CSR build ----
    hipMemsetAsync(cnt_i, 0, (size_t)NI * 4, stream);
    hipMemsetAsync(cnt_u, 0, (size_t)NU * 4, stream);
    int egrid = (E + 255) / 256;
    hist_kernel<<<egrid, 256, 0, stream>>>(eui_dst, E, cnt_i);
    hist_kernel<<<egrid, 256, 0, stream>>>(eiu_dst, E, cnt_u);
    int Bi = (NI + 1023) / 1024, Bu = (NU + 1023) / 1024;
    block_reduce_kernel<<<Bi, 256, 0, stream>>>(cnt_i, NI, bsum);
    scan_sums_kernel<<<1, 64, 0, stream>>>(bsum, boff, Bi);
    block_scan_write_kernel<<<Bi, 1024, 0, stream>>>(cnt_i, NI, boff, rp_i, cnt_i, E);
    block_reduce_kernel<<<Bu, 256, 0, stream>>>(cnt_u, NU, bsum);
    scan_sums_kernel<<<1, 64, 0, stream>>>(bsum, boff, Bu);
    block_scan_write_kernel<<<Bu, 1024, 0, stream>>>(cnt_u, NU, boff, rp_u, cnt_u, E);

    const int nb_i = (NI + RB - 1) / RB;   // 391
    const int nb_u = (NU + RB - 1) / RB;   // 782
    const int sgrid = (E + CHUNK - 1) / CHUNK;
    // item-side CSR (edges ui, dst = item)
    bucket_init_kernel<<<(nb_i + 255) / 256, 256, 0, stream>>>(rp_i, NI, nb_i, bcur_i);
    binned_scatter<<<sgrid, 256, 0, stream>>>(eui_src, eui_dst, E, nb_i, bcur_i, pairs);
    bucket_fill<<<nb_i, 256, 0, stream>>>(pairs, rp_i, NI, col_ui);
    // user-side CSR (edges iu, dst = user)
    bucket_init_kernel<<<(nb_u + 255) / 256, 256, 0, stream>>>(rp_u, NU, nb_u, bcur_u);
    binned_scatter<<<sgrid, 256, 0, stream>>>(eiu_src, eiu_dst, E, nb_u, bcur_u, pairs);
    bucket_fill<<<nb_u, 256, 0, stream>>>(pairs, rp_u, NU, col_iu);

    // ---- converts ----
    auto conv = [&](const float* in, u16* outp, size_t n) {
        int n4 = (int)(n / 4);
        f32_to_bf16_kernel<<<(n4 + 255) / 256, 256, 0, stream>>>(in, outp, n4);
    };
    conv(x_user, x_user_b, (size_t)NU * DU);
    conv(x_item, x_item_b, (size_t)NI * DI);
    conv(W1l_ui, W1l_ui_b, (size_t)HDIM * DU);
    conv(W1r_ui, W1r_ui_b, (size_t)HDIM * DI);
    conv(W1l_iu, W1l_iu_b, (size_t)HDIM * DI);
    conv(W1r_iu, W1r_iu_b, (size_t)HDIM * DU);
    conv(W2l_ui, W2l_ui_b, (size_t)HDIM * HDIM);
    conv(W2r_ui, W2r_ui_b, (size_t)HDIM * HDIM);
    conv(W2l_iu, W2l_iu_b, (size_t)HDIM * HDIM);
    conv(W2r_iu, W2r_iu_b, (size_t)HDIM * HDIM);

    // ---- layer 1 ----
    agg_mean<128><<<(NI + 3) / 4, 256, 0, stream>>>(x_user_b, rp_i, col_ui, A_i, NI);
    agg_mean<64> <<<(NU + 3) / 4, 256, 0, stream>>>(x_item_b, rp_u, col_iu, A_u, NU);
    {
        int gi = ((NI + 127) / 128) * 2;
        int gu = ((NU + 127) / 128) * 2;
        gemm_tile<128, 64, true, true><<<gi, 256, 0, stream>>>(
            A_i, x_item_b, W1l_ui_b, W1r_ui_b, b1_ui, nullptr, h_item_b, NI);
        gemm_tile<64, 128, true, true><<<gu, 256, 0, stream>>>(
            A_u, x_user_b, W1l_iu_b, W1r_iu_b, b1_iu, nullptr, h_user_b, NU);
    }

    // ---- layer 2 ----  (B_i overwrites x_user_b; B_u overwrites x_item/A_i/A_u: all dead)
    agg_mean<256><<<(NI + 3) / 4, 256, 0, stream>>>(h_user_b, rp_i, col_ui, B_i, NI);
    agg_mean<256><<<(NU + 3) / 4, 256, 0, stream>>>(h_item_b, rp_u, col_iu, B_u, NU);
    {
        int gi = ((NI + 127) / 128) * 2;
        int gu = ((NU + 127) / 128) * 2;
        gemm_tile<256, 256, false, false><<<gi, 256, 0, stream>>>(
            B_i, h_item_b, W2l_ui_b, W2r_ui_b, b2_ui, out_item, nullptr, NI);
        gemm_tile<256, 256, false, false><<<gu, 256, 0, stream>>>(
            B_u, h_user_b, W2l_iu_b, W2r_iu_b, b2_iu, out_user, nullptr, NU);
    }
}

// Round 3
// 965.056 us; speedup vs baseline: 1.5277x; 1.0245x over previous
//
#include <hip/hip_runtime.h>

// ---------------------------------------------------------------------------
// 2-layer hetero GraphSAGE, bipartite user<->item, H=256.
// Round 5: aggregation rewrite. Old agg: 8B/lane loads, one row per wave-wide
// load, unroll 4 -> only 4 outstanding row-gathers per wave (latency-bound on
// random L3 gathers). New agg: G=F/8 lanes own a row via 16B uint4 loads ->
// R=64/G rows in flight per issue (2/4/8), unroll x4 -> 8-32 outstanding
// gathers, half the load instructions. shfl_xor tree combines subgroups.
// CSR build, GEMMs (m97 structure), converts unchanged from round 4.
// ---------------------------------------------------------------------------

typedef unsigned short u16;
typedef unsigned int u32;
typedef short bf16x8 __attribute__((ext_vector_type(8)));   // 8 bf16 (4 VGPRs)
typedef float f32x4 __attribute__((ext_vector_type(4)));    // MFMA acc

constexpr int HDIM = 256;
constexpr int RB = 128;       // dst rows per bucket (b = dst >> 7)
constexpr int MAXB = 784;     // max buckets: ceil(100000/128) = 782
constexpr int CHUNK = 4096;   // edges per binned_scatter block

// ---------------- bf16 helpers ----------------

__device__ __forceinline__ float lo2f(u32 v) { union { u32 i; float f; } x; x.i = v << 16; return x.f; }
__device__ __forceinline__ float hi2f(u32 v) { union { u32 i; float f; } x; x.i = v & 0xffff0000u; return x.f; }
__device__ __forceinline__ float bf2f(u16 v) { union { u32 i; float f; } x; x.i = ((u32)v) << 16; return x.f; }
__device__ __forceinline__ u16 f2bf(float f) {  // RNE
    union { float f; u32 i; } x; x.f = f;
    return (u16)((x.i + 0x7fffu + ((x.i >> 16) & 1u)) >> 16);
}
__device__ __forceinline__ u32 pack2(float a, float b) {
    return (u32)f2bf(a) | ((u32)f2bf(b) << 16);
}

__device__ __forceinline__ void gload16(const void* g, void* l) {
    __builtin_amdgcn_global_load_lds(
        (const __attribute__((address_space(1))) unsigned int*)g,
        (__attribute__((address_space(3))) unsigned int*)l, 16, 0, 0);
}

// ---------------- CSR build ----------------

__global__ void hist_kernel(const int* __restrict__ dst, int n, int* __restrict__ cnt) {
    int i = blockIdx.x * 256 + threadIdx.x;
    if (i < n) atomicAdd(&cnt[dst[i]], 1);
}

__global__ void block_reduce_kernel(const int* __restrict__ cnt, int n, int* __restrict__ sums) {
    __shared__ int sdata[256];
    int b = blockIdx.x, t = threadIdx.x;
    int v = 0;
#pragma unroll
    for (int j = 0; j < 4; j++) {
        int idx = b * 1024 + j * 256 + t;
        if (idx < n) v += cnt[idx];
    }
    sdata[t] = v;
    __syncthreads();
    for (int s = 128; s > 0; s >>= 1) {
        if (t < s) sdata[t] += sdata[t + s];
        __syncthreads();
    }
    if (t == 0) sums[b] = sdata[0];
}

__global__ void scan_sums_kernel(const int* __restrict__ sums, int* __restrict__ offs, int B) {
    if (blockIdx.x == 0 && threadIdx.x == 0) {
        int a = 0;
        for (int i = 0; i < B; i++) { offs[i] = a; a += sums[i]; }
    }
}

__global__ void block_scan_write_kernel(const int* cnt, int n, const int* __restrict__ offs,
                                        int* __restrict__ rp, int* cursor, int total) {
    __shared__ int sdata[1024];
    int b = blockIdx.x, t = threadIdx.x;
    int idx = b * 1024 + t;
    int v = (idx < n) ? cnt[idx] : 0;
    sdata[t] = v;
    __syncthreads();
    for (int s = 1; s < 1024; s <<= 1) {
        int x = (t >= s) ? sdata[t - s] : 0;
        __syncthreads();
        sdata[t] += x;
        __syncthreads();
    }
    if (idx < n) {
        int excl = sdata[t] - v + offs[b];
        rp[idx] = excl;
        cursor[idx] = excl;
    }
    if (b == 0 && t == 0) rp[n] = total;
}

// bcur[b] = rp[b*RB]  (bucket write cursor for coarse scatter)
__global__ void bucket_init_kernel(const int* __restrict__ rp, int n, int nb,
                                   int* __restrict__ bcur) {
    int b = blockIdx.x * 256 + threadIdx.x;
    if (b < nb) {
        int row = b * RB;
        bcur[b] = rp[row < n ? row : n];
    }
}

// Pass 1: bin edges by dst-bucket. One global atomic per (block,bucket);
// run writes come from one block (one XCD) -> L2 line merge works.
__global__ __launch_bounds__(256) void binned_scatter(const int* __restrict__ src,
                                                      const int* __restrict__ dst, int E,
                                                      int nb, int* __restrict__ bcur,
                                                      uint2* __restrict__ pairs) {
    __shared__ int lcnt[MAXB];
    __shared__ int lbase[MAXB];
    const int t = threadIdx.x;
    const int chunk = blockIdx.x * CHUNK;

    for (int b = t; b < nb; b += 256) lcnt[b] = 0;
    __syncthreads();

    u32 ss[CHUNK / 256], dd[CHUNK / 256];
#pragma unroll
    for (int j = 0; j < CHUNK / 256; j++) {
        int i = chunk + j * 256 + t;
        if (i < E) {
            ss[j] = (u32)src[i];
            dd[j] = (u32)dst[i];
            atomicAdd(&lcnt[dd[j] >> 7], 1);
        } else {
            ss[j] = 0; dd[j] = 0;
        }
    }
    __syncthreads();

    for (int b = t; b < nb; b += 256) {
        int c = lcnt[b];
        lbase[b] = (c > 0) ? atomicAdd(&bcur[b], c) : 0;
    }
    __syncthreads();
    for (int b = t; b < nb; b += 256) lcnt[b] = 0;  // reuse as rank counters
    __syncthreads();

#pragma unroll
    for (int j = 0; j < CHUNK / 256; j++) {
        int i = chunk + j * 256 + t;
        if (i < E) {
            int b = (int)(dd[j] >> 7);
            int r = atomicAdd(&lcnt[b], 1);
            pairs[(size_t)lbase[b] + r] = make_uint2(ss[j], dd[j]);
        }
    }
}

// Pass 2: one block per bucket; LDS cursors; writes confined to ~16KB region.
__global__ __launch_bounds__(256) void bucket_fill(const uint2* __restrict__ pairs,
                                                   const int* __restrict__ rp, int n,
                                                   int* __restrict__ col) {
    __shared__ int lcur[RB];
    const int b = blockIdx.x;
    const int r0 = b * RB;
    const int rend = (r0 + RB < n) ? r0 + RB : n;
    const int t = threadIdx.x;
    if (t < RB) {
        int row = r0 + t;
        lcur[t] = (row < rend) ? rp[row] : 0;
    }
    __syncthreads();
    const int e0 = rp[r0];
    const int e1 = rp[rend];
    for (int j = e0 + t; j < e1; j += 256) {
        uint2 e = pairs[j];
        int p = atomicAdd(&lcur[e.y - (u32)r0], 1);
        col[p] = (int)e.x;
    }
}

// ---------------- fp32 -> bf16 convert (n must be multiple of 4) ----------------

__global__ void f32_to_bf16_kernel(const float* __restrict__ in, u16* __restrict__ out, int n4) {
    int i = blockIdx.x * 256 + threadIdx.x;
    if (i < n4) {
        float4 v = ((const float4*)in)[i];
        ((uint2*)out)[i] = make_uint2(pack2(v.x, v.y), pack2(v.z, v.w));
    }
}

// ---------------- mean aggregation v2: subgroup-per-row, 16B loads ----------------
// G = F/8 lanes own one src row (16B uint4 each); R = 64/G rows in flight per
// issue (F=256->2, 128->4, 64->8). Unroll x4 -> 4R outstanding row-gathers per
// wave. Cross-subgroup shfl_xor tree combines partial sums; lanes<G write 16B.

template <int F>
__global__ __launch_bounds__(256) void agg_mean(const u16* __restrict__ src,
                                                const int* __restrict__ rp,
                                                const int* __restrict__ col,
                                                u16* __restrict__ out, int n_dst) {
    constexpr int G = F / 8;     // lanes per row
    constexpr int R = 64 / G;    // rows in flight
    const int lane = threadIdx.x & 63;
    const int d = blockIdx.x * 4 + (threadIdx.x >> 6);
    if (d >= n_dst) return;
    const int sub = lane / G;
    const int li = lane & (G - 1);
    const int e0 = rp[d], e1 = rp[d + 1];
    const size_t lo = (size_t)li * 8;   // bf16 offset of this lane's 16B chunk

    float a[8] = {0.f, 0.f, 0.f, 0.f, 0.f, 0.f, 0.f, 0.f};
    auto add8 = [&](uint4 v) {
        a[0] += lo2f(v.x); a[1] += hi2f(v.x);
        a[2] += lo2f(v.y); a[3] += hi2f(v.y);
        a[4] += lo2f(v.z); a[5] += hi2f(v.z);
        a[6] += lo2f(v.w); a[7] += hi2f(v.w);
    };

    int ebase = e0;
    for (; ebase + 4 * R <= e1; ebase += 4 * R) {
        const int e = ebase + sub;
        int c0 = col[e];
        int c1 = col[e + R];
        int c2 = col[e + 2 * R];
        int c3 = col[e + 3 * R];
        uint4 v0 = *(const uint4*)(src + (size_t)c0 * F + lo);
        uint4 v1 = *(const uint4*)(src + (size_t)c1 * F + lo);
        uint4 v2 = *(const uint4*)(src + (size_t)c2 * F + lo);
        uint4 v3 = *(const uint4*)(src + (size_t)c3 * F + lo);
        add8(v0); add8(v1); add8(v2); add8(v3);
    }
    for (int e = ebase + sub; e < e1; e += R) {
        int c = col[e];
        uint4 v = *(const uint4*)(src + (size_t)c * F + lo);
        add8(v);
    }

    // combine the R subgroup partials (tree over lane-xor masks G..32)
#pragma unroll
    for (int m = G; m < 64; m <<= 1) {
#pragma unroll
        for (int j = 0; j < 8; j++) a[j] += __shfl_xor(a[j], m, 64);
    }

    const int deg = e1 - e0;
    const float inv = (deg > 0) ? 1.f / (float)deg : 0.f;
    if (lane < G) {
        uint4 w;
        w.x = pack2(a[0] * inv, a[1] * inv);
        w.y = pack2(a[2] * inv, a[3] * inv);
        w.z = pack2(a[4] * inv, a[5] * inv);
        w.w = pack2(a[6] * inv, a[7] * inv);
        *(uint4*)(out + (size_t)d * F + lo) = w;
    }
}

// ---------------- MFMA GEMM, m97 structure (unchanged) ----------------
// out[Mx256] = [A | X] @ [WA | WB]^T + bias   (K = KA + KB, W row-major [256][K*])
// mfma_f32_16x16x32_bf16 layouts (HW-verified):
//   A: lane holds A[m=lane&15][k=ql*8+j]
//   B: lane holds B[k=ql*8+j][n=lane&15] = W[n][k]
//   C/D: col=lane&15, row=ql*4+reg

template <int KA, int KB, bool RELU, bool OUT_BF16>
__global__ __launch_bounds__(256, 3) void gemm_tile(const u16* __restrict__ A,
                                                    const u16* __restrict__ X,
                                                    const u16* __restrict__ WA,
                                                    const u16* __restrict__ WB,
                                                    const float* __restrict__ bias,
                                                    float* __restrict__ outF,
                                                    u16* __restrict__ outB, int M) {
    constexpr int KT = KA + KB;
    constexpr int NKT = KT / 32;
    __shared__ __align__(16) u16 Al[128 * 32];   // 8 KB
    __shared__ __align__(16) u16 Wl[128 * 32];   // 8 KB

    // XCD-aware bijective swizzle (m204)
    const int nwg = gridDim.x;
    const int b = blockIdx.x;
    const int q = nwg >> 3, r = nwg & 7;
    const int xcd = b & 7, within = b >> 3;
    const int logical = (xcd < r ? xcd * (q + 1) : r * (q + 1) + (xcd - r) * q) + within;
    const int mb = logical >> 1;
    const int nb = logical & 1;
    const int row0 = mb * 128;
    const int ncol0 = nb * 128;

    const int tid = threadIdx.x;
    const int lane = tid & 63;
    const int wid = tid >> 6;
    const int wr = wid >> 1;
    const int wc = wid & 1;
    const int ml = lane & 15;
    const int ql = lane >> 4;
    const int lrow4 = lane >> 2;
    const int lcol8 = (lane & 3) * 8;

    f32x4 acc[4][4];
#pragma unroll
    for (int m = 0; m < 4; m++)
#pragma unroll
        for (int n = 0; n < 4; n++) acc[m][n] = {0.f, 0.f, 0.f, 0.f};

    const int s0 = wid * 2;

#pragma unroll
    for (int kt = 0; kt < NKT; ++kt) {
        const int kk = kt * 32;
#pragma unroll
        for (int j = 0; j < 2; ++j) {
            const int s = s0 + j;
            int gr = row0 + s * 16 + lrow4;
            gr = (gr < M) ? gr : (M - 1);
            const u16* gp = (kk < KA) ? (A + (size_t)gr * KA + (kk + lcol8))
                                      : (X + (size_t)gr * KB + (kk - KA + lcol8));
            gload16(gp, &Al[s * 512]);
        }
#pragma unroll
        for (int j = 0; j < 2; ++j) {
            const int s = s0 + j;
            const int gn = ncol0 + s * 16 + lrow4;
            const u16* gp = (kk < KA) ? (WA + (size_t)gn * KA + (kk + lcol8))
                                      : (WB + (size_t)gn * KB + (kk - KA + lcol8));
            gload16(gp, &Wl[s * 512]);
        }
        __syncthreads();

        bf16x8 af[4], wf[4];
#pragma unroll
        for (int m = 0; m < 4; m++)
            af[m] = *(const bf16x8*)&Al[(wr * 64 + m * 16 + ml) * 32 + ql * 8];
#pragma unroll
        for (int n = 0; n < 4; n++)
            wf[n] = *(const bf16x8*)&Wl[(wc * 64 + n * 16 + ml) * 32 + ql * 8];
#pragma unroll
        for (int m = 0; m < 4; m++)
#pragma unroll
            for (int n = 0; n < 4; n++)
                acc[m][n] = __builtin_amdgcn_mfma_f32_16x16x32_bf16(af[m], wf[n], acc[m][n], 0, 0, 0);
        __syncthreads();
    }

#pragma unroll
    for (int n = 0; n < 4; n++) {
        const int gcol = ncol0 + wc * 64 + n * 16 + ml;
        const float bv = bias[gcol];
#pragma unroll
        for (int m = 0; m < 4; m++) {
            const int gr0 = row0 + wr * 64 + m * 16 + ql * 4;
#pragma unroll
            for (int rr = 0; rr < 4; rr++) {
                const int grow = gr0 + rr;
                if (grow >= M) continue;
                float v = acc[m][n][rr] + bv;
                if (RELU) v = fmaxf(v, 0.f);
                if (OUT_BF16) outB[(size_t)grow * HDIM + gcol] = f2bf(v);
                else          outF[(size_t)grow * HDIM + gcol] = v;
            }
        }
    }
}

// ---------------- host ----------------

extern "C" void kernel_launch(void* const* d_in, const int* in_sizes, int n_in,
                              void* d_out, int out_size, void* d_ws, size_t ws_size,
                              hipStream_t stream) {
    const float* x_user = (const float*)d_in[0];
    const float* x_item = (const float*)d_in[1];
    const int* eui_src = (const int*)d_in[2];
    const int* eui_dst = (const int*)d_in[3];
    const int* eiu_src = (const int*)d_in[4];
    const int* eiu_dst = (const int*)d_in[5];
    const float* W1l_ui = (const float*)d_in[6];
    const float* b1_ui  = (const float*)d_in[7];
    const float* W1r_ui = (const float*)d_in[8];
    const float* W1l_iu = (const float*)d_in[9];
    const float* b1_iu  = (const float*)d_in[10];
    const float* W1r_iu = (const float*)d_in[11];
    const float* W2l_ui = (const float*)d_in[12];
    const float* b2_ui  = (const float*)d_in[13];
    const float* W2r_ui = (const float*)d_in[14];
    const float* W2l_iu = (const float*)d_in[15];
    const float* b2_iu  = (const float*)d_in[16];
    const float* W2r_iu = (const float*)d_in[17];

    const int DU = 128, DI = 64;
    const int NU = in_sizes[0] / DU;   // 100000
    const int NI = in_sizes[1] / DI;   // 50000
    const int E  = in_sizes[2];        // 1600000

    // ---- carve workspace (256B aligned) ----
    char* base = (char*)d_ws;
    size_t off = 0;
    auto carve = [&](size_t bytes) -> char* {
        char* p = base + off;
        off += (bytes + 255) & ~(size_t)255;
        return p;
    };
    int* cnt_i  = (int*)carve((size_t)NI * 4);
    int* cnt_u  = (int*)carve((size_t)NU * 4);
    int* rp_i   = (int*)carve((size_t)(NI + 1) * 4);
    int* rp_u   = (int*)carve((size_t)(NU + 1) * 4);
    int* col_ui = (int*)carve((size_t)E * 4);
    int* col_iu = (int*)carve((size_t)E * 4);
    int* bsum   = (int*)carve(1024 * 4);
    int* boff   = (int*)carve(1024 * 4);
    int* bcur_i = (int*)carve(MAXB * 4);
    int* bcur_u = (int*)carve(MAXB * 4);
    // bf16 weights
    u16* W1l_ui_b = (u16*)carve((size_t)HDIM * DU * 2);
    u16* W1r_ui_b = (u16*)carve((size_t)HDIM * DI * 2);
    u16* W1l_iu_b = (u16*)carve((size_t)HDIM * DI * 2);
    u16* W1r_iu_b = (u16*)carve((size_t)HDIM * DU * 2);
    u16* W2l_ui_b = (u16*)carve((size_t)HDIM * HDIM * 2);
    u16* W2r_ui_b = (u16*)carve((size_t)HDIM * HDIM * 2);
    u16* W2l_iu_b = (u16*)carve((size_t)HDIM * HDIM * 2);
    u16* W2r_iu_b = (u16*)carve((size_t)HDIM * HDIM * 2);
    // slot1 (25.6 MB): x_user_bf, later B_i (mean of h_user, [NI x 256])
    char* slot1 = carve((size_t)NU * DU * 2);          // == NI*HDIM*2
    u16* x_user_b = (u16*)slot1;
    u16* B_i      = (u16*)slot1;
    // slotB (51.2 MB): x_item_bf + A_i + A_u, later B_u ([NU x 256])
    char* slotB = carve((size_t)NU * HDIM * 2);
    u16* x_item_b = (u16*)slotB;                               // NI*64*2  = 6.4 MB
    u16* A_i      = (u16*)(slotB + (size_t)NI * DI * 2);       // NI*128*2 = 12.8 MB
    u16* A_u      = (u16*)(slotB + (size_t)NI * DI * 2 + (size_t)NI * DU * 2);  // NU*64*2
    u16* B_u      = (u16*)slotB;
    // h buffers (persist through layer 2)
    u16* h_item_b = (u16*)carve((size_t)NI * HDIM * 2);  // 25.6 MB
    u16* h_user_b = (u16*)carve((size_t)NU * HDIM * 2);  // 51.2 MB

    // pairs scratch (12.8 MB) aliases h_user_b: dead until layer-1 gemm (same stream)
    uint2* pairs = (uint2*)h_user_b;

    float* out_user = (float*)d_out;
    float* out_item = (float*)d_out + (size_t)NU * HDIM;

    // ---- CSR build ----
    hipMemsetAsync(cnt_i, 0, (size_t)NI * 4, stream);
    hipMemsetAsync(cnt_u, 0, (size_t)NU * 4, stream);
    int egrid = (E + 255) / 256;
    hist_kernel<<<egrid, 256, 0, stream>>>(eui_dst, E, cnt_i);
    hist_kernel<<<egrid, 256, 0, stream>>>(eiu_dst, E, cnt_u);
    int Bi = (NI + 1023) / 1024, Bu = (NU + 1023) / 1024;
    block_reduce_kernel<<<Bi, 256, 0, stream>>>(cnt_i, NI, bsum);
    scan_sums_kernel<<<1, 64, 0, stream>>>(bsum, boff, Bi);
    block_scan_write_kernel<<<Bi, 1024, 0, stream>>>(cnt_i, NI, boff, rp_i, cnt_i, E);
    block_reduce_kernel<<<Bu, 256, 0, stream>>>(cnt_u, NU, bsum);
    scan_sums_kernel<<<1, 64, 0, stream>>>(bsum, boff, Bu);
    block_scan_write_kernel<<<Bu, 1024, 0, stream>>>(cnt_u, NU, boff, rp_u, cnt_u, E);

    const int nb_i = (NI + RB - 1) / RB;   // 391
    const int nb_u = (NU + RB - 1) / RB;   // 782
    const int sgrid = (E + CHUNK - 1) / CHUNK;
    bucket_init_kernel<<<(nb_i + 255) / 256, 256, 0, stream>>>(rp_i, NI, nb_i, bcur_i);
    binned_scatter<<<sgrid, 256, 0, stream>>>(eui_src, eui_dst, E, nb_i, bcur_i, pairs);
    bucket_fill<<<nb_i, 256, 0, stream>>>(pairs, rp_i, NI, col_ui);
    bucket_init_kernel<<<(nb_u + 255) / 256, 256, 0, stream>>>(rp_u, NU, nb_u, bcur_u);
    binned_scatter<<<sgrid, 256, 0, stream>>>(eiu_src, eiu_dst, E, nb_u, bcur_u, pairs);
    bucket_fill<<<nb_u, 256, 0, stream>>>(pairs, rp_u, NU, col_iu);

    // ---- converts ----
    auto conv = [&](const float* in, u16* outp, size_t n) {
        int n4 = (int)(n / 4);
        f32_to_bf16_kernel<<<(n4 + 255) / 256, 256, 0, stream>>>(in, outp, n4);
    };
    conv(x_user, x_user_b, (size_t)NU * DU);
    conv(x_item, x_item_b, (size_t)NI * DI);
    conv(W1l_ui, W1l_ui_b, (size_t)HDIM * DU);
    conv(W1r_ui, W1r_ui_b, (size_t)HDIM * DI);
    conv(W1l_iu, W1l_iu_b, (size_t)HDIM * DI);
    conv(W1r_iu, W1r_iu_b, (size_t)HDIM * DU);
    conv(W2l_ui, W2l_ui_b, (size_t)HDIM * HDIM);
    conv(W2r_ui, W2r_ui_b, (size_t)HDIM * HDIM);
    conv(W2l_iu, W2l_iu_b, (size_t)HDIM * HDIM);
    conv(W2r_iu, W2r_iu_b, (size_t)HDIM * HDIM);

    // ---- layer 1 ----
    agg_mean<128><<<(NI + 3) / 4, 256, 0, stream>>>(x_user_b, rp_i, col_ui, A_i, NI);
    agg_mean<64> <<<(NU + 3) / 4, 256, 0, stream>>>(x_item_b, rp_u, col_iu, A_u, NU);
    {
        int gi = ((NI + 127) / 128) * 2;
        int gu = ((NU + 127) / 128) * 2;
        gemm_tile<128, 64, true, true><<<gi, 256, 0, stream>>>(
            A_i, x_item_b, W1l_ui_b, W1r_ui_b, b1_ui, nullptr, h_item_b, NI);
        gemm_tile<64, 128, true, true><<<gu, 256, 0, stream>>>(
            A_u, x_user_b, W1l_iu_b, W1r_iu_b, b1_iu, nullptr, h_user_b, NU);
    }

    // ---- layer 2 ----  (B_i overwrites x_user_b; B_u overwrites x_item/A_i/A_u: all dead)
    agg_mean<256><<<(NI + 3) / 4, 256, 0, stream>>>(h_user_b, rp_i, col_ui, B_i, NI);
    agg_mean<256><<<(NU + 3) / 4, 256, 0, stream>>>(h_item_b, rp_u, col_iu, B_u, NU);
    {
        int gi = ((NI + 127) / 128) * 2;
        int gu = ((NU + 127) / 128) * 2;
        gemm_tile<256, 256, false, false><<<gi, 256, 0, stream>>>(
            B_i, h_item_b, W2l_ui_b, W2r_ui_b, b2_ui, out_item, nullptr, NI);
        gemm_tile<256, 256, false, false><<<gu, 256, 0, stream>>>(
            B_u, h_user_b, W2l_iu_b, W2r_iu_b, b2_iu, out_user, nullptr, NU);
    }
}

// Round 4
// 824.787 us; speedup vs baseline: 1.7875x; 1.1701x over previous
//
#include <hip/hip_runtime.h>

// ---------------------------------------------------------------------------
// 2-layer hetero GraphSAGE, bipartite user<->item, H=256.
// Round 6: tail-latency attack. (a) CSR build reworked 16 launches -> 5:
// LDS bucket histogram + parallel bucket scan + merged binned scatter +
// bucket_fill2 that derives rp AND fills col from bucket-grouped pairs
// (eliminates hist's 1.6M random global atomics x2, the serial scans, and
// block_scan_write). (b) 10 convert launches -> 1 multi_convert. (c) layer-2
// aggs merged into one dispatch; agg gather depth 4->8 (latency probe).
// GEMMs (m97 structure) byte-identical to round 5.
// ---------------------------------------------------------------------------

typedef unsigned short u16;
typedef unsigned int u32;
typedef short bf16x8 __attribute__((ext_vector_type(8)));   // 8 bf16 (4 VGPRs)
typedef float f32x4 __attribute__((ext_vector_type(4)));    // MFMA acc

constexpr int HDIM = 256;
constexpr int RB = 128;       // dst rows per bucket (b = dst >> 7)
constexpr int MAXB = 784;     // max buckets: ceil(100000/128) = 782
constexpr int CHUNK = 4096;   // edges per scatter block

// ---------------- bf16 helpers ----------------

__device__ __forceinline__ float lo2f(u32 v) { union { u32 i; float f; } x; x.i = v << 16; return x.f; }
__device__ __forceinline__ float hi2f(u32 v) { union { u32 i; float f; } x; x.i = v & 0xffff0000u; return x.f; }
__device__ __forceinline__ u16 f2bf(float f) {  // RNE
    union { float f; u32 i; } x; x.f = f;
    return (u16)((x.i + 0x7fffu + ((x.i >> 16) & 1u)) >> 16);
}
__device__ __forceinline__ u32 pack2(float a, float b) {
    return (u32)f2bf(a) | ((u32)f2bf(b) << 16);
}

__device__ __forceinline__ void gload16(const void* g, void* l) {
    __builtin_amdgcn_global_load_lds(
        (const __attribute__((address_space(1))) unsigned int*)g,
        (__attribute__((address_space(3))) unsigned int*)l, 16, 0, 0);
}

// ---------------- CSR build v3 (5 launches total) ----------------

// Pass 0: per-bucket edge counts. LDS histogram per block; one global atomic
// per (block, nonzero bucket) instead of one per edge.
__global__ __launch_bounds__(256) void bucket_count(const int* __restrict__ dst0, int nb0,
                                                    int* __restrict__ bc0,
                                                    const int* __restrict__ dst1, int nb1,
                                                    int* __restrict__ bc1,
                                                    int E, int sgrid) {
    __shared__ int lcnt[MAXB];
    int b = blockIdx.x;
    const int* dst; int nb; int* bc;
    if (b < sgrid) { dst = dst0; nb = nb0; bc = bc0; }
    else           { b -= sgrid; dst = dst1; nb = nb1; bc = bc1; }
    const int t = threadIdx.x;
    for (int i = t; i < nb; i += 256) lcnt[i] = 0;
    __syncthreads();
    const int base = b * CHUNK;
#pragma unroll
    for (int j = 0; j < CHUNK / 256; j++) {
        int i = base + j * 256 + t;
        if (i < E) atomicAdd(&lcnt[dst[i] >> 7], 1);
    }
    __syncthreads();
    for (int i = t; i < nb; i += 256) {
        int c = lcnt[i];
        if (c) atomicAdd(&bc[i], c);
    }
}

// Pass 1: parallel exclusive scan of bucket counts (both graphs, one block).
__global__ __launch_bounds__(1024) void bucket_scan(const int* __restrict__ bc0,
                                                    int* __restrict__ base0,
                                                    int* __restrict__ bcur0, int nb0,
                                                    const int* __restrict__ bc1,
                                                    int* __restrict__ base1,
                                                    int* __restrict__ bcur1, int nb1) {
    __shared__ int s[1024];
    const int t = threadIdx.x;
    // graph 0
    int own = (t < nb0) ? bc0[t] : 0;
    s[t] = own;
    __syncthreads();
    for (int st = 1; st < 1024; st <<= 1) {
        int v = (t >= st) ? s[t - st] : 0;
        __syncthreads();
        s[t] += v;
        __syncthreads();
    }
    if (t < nb0) { int ex = s[t] - own; base0[t] = ex; bcur0[t] = ex; }
    if (t == 0) base0[nb0] = s[1023];
    __syncthreads();
    // graph 1
    own = (t < nb1) ? bc1[t] : 0;
    s[t] = own;
    __syncthreads();
    for (int st = 1; st < 1024; st <<= 1) {
        int v = (t >= st) ? s[t - st] : 0;
        __syncthreads();
        s[t] += v;
        __syncthreads();
    }
    if (t < nb1) { int ex = s[t] - own; base1[t] = ex; bcur1[t] = ex; }
    if (t == 0) base1[nb1] = s[1023];
}

// Pass 2: bin edges into bucket-grouped (src,dst) pair runs. One global atomic
// per (block,bucket); each run written by one block (one XCD) -> lines merge.
__global__ __launch_bounds__(256) void binned_scatter2(
    const int* __restrict__ src0, const int* __restrict__ dst0, int nb0,
    int* __restrict__ bcur0, uint2* __restrict__ pairs0,
    const int* __restrict__ src1, const int* __restrict__ dst1, int nb1,
    int* __restrict__ bcur1, uint2* __restrict__ pairs1,
    int E, int sgrid) {
    __shared__ int lcnt[MAXB];
    __shared__ int lbase[MAXB];
    int b = blockIdx.x;
    const int *src, *dst; int nb; int* bcur; uint2* pairs;
    if (b < sgrid) { src = src0; dst = dst0; nb = nb0; bcur = bcur0; pairs = pairs0; }
    else           { b -= sgrid; src = src1; dst = dst1; nb = nb1; bcur = bcur1; pairs = pairs1; }
    const int t = threadIdx.x;
    const int chunk = b * CHUNK;

    for (int i = t; i < nb; i += 256) lcnt[i] = 0;
    __syncthreads();

    u32 ss[CHUNK / 256], dd[CHUNK / 256];
#pragma unroll
    for (int j = 0; j < CHUNK / 256; j++) {
        int i = chunk + j * 256 + t;
        if (i < E) {
            ss[j] = (u32)src[i];
            dd[j] = (u32)dst[i];
            atomicAdd(&lcnt[dd[j] >> 7], 1);
        } else {
            ss[j] = 0; dd[j] = 0;
        }
    }
    __syncthreads();

    for (int i = t; i < nb; i += 256) {
        int c = lcnt[i];
        lbase[i] = (c > 0) ? atomicAdd(&bcur[i], c) : 0;
    }
    __syncthreads();
    for (int i = t; i < nb; i += 256) lcnt[i] = 0;  // reuse as rank counters
    __syncthreads();

#pragma unroll
    for (int j = 0; j < CHUNK / 256; j++) {
        int i = chunk + j * 256 + t;
        if (i < E) {
            int bb = (int)(dd[j] >> 7);
            int r = atomicAdd(&lcnt[bb], 1);
            pairs[(size_t)lbase[bb] + r] = make_uint2(ss[j], dd[j]);
        }
    }
}

// Pass 3: one block per bucket. Counts per-row in LDS, scans -> writes rp for
// its 128 rows, then fills col with LDS cursors (writes confined to ~16KB).
__global__ __launch_bounds__(256) void bucket_fill2(
    const uint2* __restrict__ pairs0, const int* __restrict__ base0, int nb0, int n0,
    int* __restrict__ rp0, int* __restrict__ col0,
    const uint2* __restrict__ pairs1, const int* __restrict__ base1, int n1,
    int* __restrict__ rp1, int* __restrict__ col1) {
    __shared__ int rcnt[RB];
    __shared__ int excl[RB];
    __shared__ int lcur[RB];
    int b = blockIdx.x;
    const uint2* pairs; const int* bb; int n; int* rp; int* col;
    if (b < nb0) { pairs = pairs0; bb = base0; n = n0; rp = rp0; col = col0; }
    else         { b -= nb0; pairs = pairs1; bb = base1; n = n1; rp = rp1; col = col1; }
    const int t = threadIdx.x;
    const int r0 = b * RB;
    const int e0 = bb[b], e1 = bb[b + 1];

    if (t < RB) rcnt[t] = 0;
    __syncthreads();
    for (int j = e0 + t; j < e1; j += 256) atomicAdd(&rcnt[pairs[j].y & (RB - 1)], 1);
    __syncthreads();
    int own = (t < RB) ? rcnt[t] : 0;
    if (t < RB) excl[t] = own;
    __syncthreads();
    for (int st = 1; st < RB; st <<= 1) {
        int v = (t < RB && t >= st) ? excl[t - st] : 0;
        __syncthreads();
        if (t < RB) excl[t] += v;
        __syncthreads();
    }
    if (t < RB) {
        int ex = e0 + excl[t] - own;   // exclusive within bucket + bucket base
        int row = r0 + t;
        if (row < n) rp[row] = ex;
        lcur[t] = ex;
    }
    if (t == 0 && r0 + RB >= n) rp[n] = e1;  // last bucket: e1 == E
    __syncthreads();
    for (int j = e0 + t; j < e1; j += 256) {
        uint2 e = pairs[j];
        int p = atomicAdd(&lcur[e.y & (RB - 1)], 1);
        col[p] = (int)e.x;
    }
}

// ---------------- fused fp32 -> bf16 convert (all 10 tensors, 1 launch) ----

struct ConvSeg { const float* in; u16* out; u32 n4; u32 pad; };
struct ConvArgs { ConvSeg s[10]; u32 tot; };

__global__ __launch_bounds__(256) void multi_convert(ConvArgs a) {
    for (u32 i = blockIdx.x * 256 + threadIdx.x; i < a.tot; i += gridDim.x * 256) {
        u32 r = i;
        int sg = 0;
        while (r >= a.s[sg].n4) { r -= a.s[sg].n4; sg++; }
        float4 v = ((const float4*)a.s[sg].in)[r];
        ((uint2*)a.s[sg].out)[r] = make_uint2(pack2(v.x, v.y), pack2(v.z, v.w));
    }
}

// ---------------- mean aggregation: subgroup-per-row, 16B loads, depth 8 ----
// G = F/8 lanes own one src row (16B uint4 each); R = 64/G rows in flight per
// issue (F=256->2, 128->4, 64->8). Unroll x8 -> 8R outstanding row-gathers.

template <int F>
__device__ __forceinline__ void agg_row(const u16* __restrict__ src, const int* __restrict__ rp,
                                        const int* __restrict__ col, u16* __restrict__ out,
                                        int n_dst, int d) {
    constexpr int G = F / 8;     // lanes per row
    constexpr int R = 64 / G;    // rows in flight per issue
    const int lane = threadIdx.x & 63;
    if (d >= n_dst) return;
    const int sub = lane / G;
    const int li = lane & (G - 1);
    const int e0 = rp[d], e1 = rp[d + 1];
    const size_t lo = (size_t)li * 8;   // bf16 offset of this lane's 16B chunk

    float a[8] = {0.f, 0.f, 0.f, 0.f, 0.f, 0.f, 0.f, 0.f};
    auto add8 = [&](uint4 v) {
        a[0] += lo2f(v.x); a[1] += hi2f(v.x);
        a[2] += lo2f(v.y); a[3] += hi2f(v.y);
        a[4] += lo2f(v.z); a[5] += hi2f(v.z);
        a[6] += lo2f(v.w); a[7] += hi2f(v.w);
    };

    int ebase = e0;
    for (; ebase + 8 * R <= e1; ebase += 8 * R) {
        int c[8];
#pragma unroll
        for (int k = 0; k < 8; k++) c[k] = col[ebase + sub + k * R];
        uint4 v[8];
#pragma unroll
        for (int k = 0; k < 8; k++) v[k] = *(const uint4*)(src + (size_t)c[k] * F + lo);
#pragma unroll
        for (int k = 0; k < 8; k++) add8(v[k]);
    }
    for (; ebase + 4 * R <= e1; ebase += 4 * R) {
        int c[4];
#pragma unroll
        for (int k = 0; k < 4; k++) c[k] = col[ebase + sub + k * R];
        uint4 v[4];
#pragma unroll
        for (int k = 0; k < 4; k++) v[k] = *(const uint4*)(src + (size_t)c[k] * F + lo);
#pragma unroll
        for (int k = 0; k < 4; k++) add8(v[k]);
    }
    for (int e = ebase + sub; e < e1; e += R) {
        uint4 v = *(const uint4*)(src + (size_t)col[e] * F + lo);
        add8(v);
    }

    // combine the R subgroup partials (tree over lane-xor masks G..32)
#pragma unroll
    for (int m = G; m < 64; m <<= 1) {
#pragma unroll
        for (int j = 0; j < 8; j++) a[j] += __shfl_xor(a[j], m, 64);
    }

    const int deg = e1 - e0;
    const float inv = (deg > 0) ? 1.f / (float)deg : 0.f;
    if (lane < G) {
        uint4 w;
        w.x = pack2(a[0] * inv, a[1] * inv);
        w.y = pack2(a[2] * inv, a[3] * inv);
        w.z = pack2(a[4] * inv, a[5] * inv);
        w.w = pack2(a[6] * inv, a[7] * inv);
        *(uint4*)(out + (size_t)d * F + lo) = w;
    }
}

template <int F>
__global__ __launch_bounds__(256) void agg_mean(const u16* __restrict__ src,
                                                const int* __restrict__ rp,
                                                const int* __restrict__ col,
                                                u16* __restrict__ out, int n_dst) {
    agg_row<F>(src, rp, col, out, n_dst, blockIdx.x * 4 + (threadIdx.x >> 6));
}

// both layer-2 aggregations (F=256) in one dispatch
__global__ __launch_bounds__(256) void agg_mean256_dual(
    const u16* __restrict__ src0, const int* __restrict__ rp0, const int* __restrict__ col0,
    u16* __restrict__ out0, int n0, int g0,
    const u16* __restrict__ src1, const int* __restrict__ rp1, const int* __restrict__ col1,
    u16* __restrict__ out1, int n1) {
    const int b = blockIdx.x;
    if (b < g0) agg_row<256>(src0, rp0, col0, out0, n0, b * 4 + (threadIdx.x >> 6));
    else        agg_row<256>(src1, rp1, col1, out1, n1, (b - g0) * 4 + (threadIdx.x >> 6));
}

// ---------------- MFMA GEMM, m97 structure (unchanged) ----------------
// out[Mx256] = [A | X] @ [WA | WB]^T + bias   (K = KA + KB, W row-major [256][K*])
// mfma_f32_16x16x32_bf16 layouts (HW-verified):
//   A: lane holds A[m=lane&15][k=ql*8+j]
//   B: lane holds B[k=ql*8+j][n=lane&15] = W[n][k]
//   C/D: col=lane&15, row=ql*4+reg

template <int KA, int KB, bool RELU, bool OUT_BF16>
__global__ __launch_bounds__(256, 3) void gemm_tile(const u16* __restrict__ A,
                                                    const u16* __restrict__ X,
                                                    const u16* __restrict__ WA,
                                                    const u16* __restrict__ WB,
                                                    const float* __restrict__ bias,
                                                    float* __restrict__ outF,
                                                    u16* __restrict__ outB, int M) {
    constexpr int KT = KA + KB;
    constexpr int NKT = KT / 32;
    __shared__ __align__(16) u16 Al[128 * 32];   // 8 KB
    __shared__ __align__(16) u16 Wl[128 * 32];   // 8 KB

    // XCD-aware bijective swizzle (m204)
    const int nwg = gridDim.x;
    const int b = blockIdx.x;
    const int q = nwg >> 3, r = nwg & 7;
    const int xcd = b & 7, within = b >> 3;
    const int logical = (xcd < r ? xcd * (q + 1) : r * (q + 1) + (xcd - r) * q) + within;
    const int mb = logical >> 1;
    const int nb = logical & 1;
    const int row0 = mb * 128;
    const int ncol0 = nb * 128;

    const int tid = threadIdx.x;
    const int lane = tid & 63;
    const int wid = tid >> 6;
    const int wr = wid >> 1;
    const int wc = wid & 1;
    const int ml = lane & 15;
    const int ql = lane >> 4;
    const int lrow4 = lane >> 2;
    const int lcol8 = (lane & 3) * 8;

    f32x4 acc[4][4];
#pragma unroll
    for (int m = 0; m < 4; m++)
#pragma unroll
        for (int n = 0; n < 4; n++) acc[m][n] = {0.f, 0.f, 0.f, 0.f};

    const int s0 = wid * 2;

#pragma unroll
    for (int kt = 0; kt < NKT; ++kt) {
        const int kk = kt * 32;
#pragma unroll
        for (int j = 0; j < 2; ++j) {
            const int s = s0 + j;
            int gr = row0 + s * 16 + lrow4;
            gr = (gr < M) ? gr : (M - 1);
            const u16* gp = (kk < KA) ? (A + (size_t)gr * KA + (kk + lcol8))
                                      : (X + (size_t)gr * KB + (kk - KA + lcol8));
            gload16(gp, &Al[s * 512]);
        }
#pragma unroll
        for (int j = 0; j < 2; ++j) {
            const int s = s0 + j;
            const int gn = ncol0 + s * 16 + lrow4;
            const u16* gp = (kk < KA) ? (WA + (size_t)gn * KA + (kk + lcol8))
                                      : (WB + (size_t)gn * KB + (kk - KA + lcol8));
            gload16(gp, &Wl[s * 512]);
        }
        __syncthreads();

        bf16x8 af[4], wf[4];
#pragma unroll
        for (int m = 0; m < 4; m++)
            af[m] = *(const bf16x8*)&Al[(wr * 64 + m * 16 + ml) * 32 + ql * 8];
#pragma unroll
        for (int n = 0; n < 4; n++)
            wf[n] = *(const bf16x8*)&Wl[(wc * 64 + n * 16 + ml) * 32 + ql * 8];
#pragma unroll
        for (int m = 0; m < 4; m++)
#pragma unroll
            for (int n = 0; n < 4; n++)
                acc[m][n] = __builtin_amdgcn_mfma_f32_16x16x32_bf16(af[m], wf[n], acc[m][n], 0, 0, 0);
        __syncthreads();
    }

#pragma unroll
    for (int n = 0; n < 4; n++) {
        const int gcol = ncol0 + wc * 64 + n * 16 + ml;
        const float bv = bias[gcol];
#pragma unroll
        for (int m = 0; m < 4; m++) {
            const int gr0 = row0 + wr * 64 + m * 16 + ql * 4;
#pragma unroll
            for (int rr = 0; rr < 4; rr++) {
                const int grow = gr0 + rr;
                if (grow >= M) continue;
                float v = acc[m][n][rr] + bv;
                if (RELU) v = fmaxf(v, 0.f);
                if (OUT_BF16) outB[(size_t)grow * HDIM + gcol] = f2bf(v);
                else          outF[(size_t)grow * HDIM + gcol] = v;
            }
        }
    }
}

// ---------------- host ----------------

extern "C" void kernel_launch(void* const* d_in, const int* in_sizes, int n_in,
                              void* d_out, int out_size, void* d_ws, size_t ws_size,
                              hipStream_t stream) {
    const float* x_user = (const float*)d_in[0];
    const float* x_item = (const float*)d_in[1];
    const int* eui_src = (const int*)d_in[2];
    const int* eui_dst = (const int*)d_in[3];
    const int* eiu_src = (const int*)d_in[4];
    const int* eiu_dst = (const int*)d_in[5];
    const float* W1l_ui = (const float*)d_in[6];
    const float* b1_ui  = (const float*)d_in[7];
    const float* W1r_ui = (const float*)d_in[8];
    const float* W1l_iu = (const float*)d_in[9];
    const float* b1_iu  = (const float*)d_in[10];
    const float* W1r_iu = (const float*)d_in[11];
    const float* W2l_ui = (const float*)d_in[12];
    const float* b2_ui  = (const float*)d_in[13];
    const float* W2r_ui = (const float*)d_in[14];
    const float* W2l_iu = (const float*)d_in[15];
    const float* b2_iu  = (const float*)d_in[16];
    const float* W2r_iu = (const float*)d_in[17];

    const int DU = 128, DI = 64;
    const int NU = in_sizes[0] / DU;   // 100000
    const int NI = in_sizes[1] / DI;   // 50000
    const int E  = in_sizes[2];        // 1600000

    // ---- carve workspace (256B aligned) ----
    char* base = (char*)d_ws;
    size_t off = 0;
    auto carve = [&](size_t bytes) -> char* {
        char* p = base + off;
        off += (bytes + 255) & ~(size_t)255;
        return p;
    };
    int* rp_i   = (int*)carve((size_t)(NI + 1) * 4);
    int* rp_u   = (int*)carve((size_t)(NU + 1) * 4);
    int* col_ui = (int*)carve((size_t)E * 4);
    int* col_iu = (int*)carve((size_t)E * 4);
    int* bc     = (int*)carve((size_t)2 * MAXB * 4);     // bucket counts (both graphs)
    int* bc_i   = bc;
    int* bc_u   = bc + MAXB;
    int* base_i = (int*)carve((size_t)(MAXB + 1) * 4);
    int* base_u = (int*)carve((size_t)(MAXB + 1) * 4);
    int* bcur_i = (int*)carve(MAXB * 4);
    int* bcur_u = (int*)carve(MAXB * 4);
    // bf16 weights
    u16* W1l_ui_b = (u16*)carve((size_t)HDIM * DU * 2);
    u16* W1r_ui_b = (u16*)carve((size_t)HDIM * DI * 2);
    u16* W1l_iu_b = (u16*)carve((size_t)HDIM * DI * 2);
    u16* W1r_iu_b = (u16*)carve((size_t)HDIM * DU * 2);
    u16* W2l_ui_b = (u16*)carve((size_t)HDIM * HDIM * 2);
    u16* W2r_ui_b = (u16*)carve((size_t)HDIM * HDIM * 2);
    u16* W2l_iu_b = (u16*)carve((size_t)HDIM * HDIM * 2);
    u16* W2r_iu_b = (u16*)carve((size_t)HDIM * HDIM * 2);
    // slot1 (25.6 MB): x_user_bf, later B_i (mean of h_user, [NI x 256])
    char* slot1 = carve((size_t)NU * DU * 2);          // == NI*HDIM*2
    u16* x_user_b = (u16*)slot1;
    u16* B_i      = (u16*)slot1;
    // slotB (51.2 MB): x_item_bf + A_i + A_u, later B_u ([NU x 256])
    char* slotB = carve((size_t)NU * HDIM * 2);
    u16* x_item_b = (u16*)slotB;                               // NI*64*2  = 6.4 MB
    u16* A_i      = (u16*)(slotB + (size_t)NI * DI * 2);       // NI*128*2 = 12.8 MB
    u16* A_u      = (u16*)(slotB + (size_t)NI * DI * 2 + (size_t)NI * DU * 2);  // NU*64*2
    u16* B_u      = (u16*)slotB;
    // h buffers (persist through layer 2)
    u16* h_item_b = (u16*)carve((size_t)NI * HDIM * 2);  // 25.6 MB
    u16* h_user_b = (u16*)carve((size_t)NU * HDIM * 2);  // 51.2 MB

    // pairs scratch (2 x 12.8 MB) aliases h_user_b (51.2 MB): dead until L1 gemm
    uint2* pairs_i = (uint2*)h_user_b;
    uint2* pairs_u = (uint2*)(h_user_b + (size_t)E * 4);   // E*8 bytes after start

    float* out_user = (float*)d_out;
    float* out_item = (float*)d_out + (size_t)NU * HDIM;

    const int nb_i = (NI + RB - 1) / RB;   // 391
    const int nb_u = (NU + RB - 1) / RB;   // 782
    const int sgrid = (E + CHUNK - 1) / CHUNK;

    // ---- CSR build (5 launches) ----
    hipMemsetAsync(bc, 0, (size_t)2 * MAXB * 4, stream);
    bucket_count<<<2 * sgrid, 256, 0, stream>>>(eui_dst, nb_i, bc_i, eiu_dst, nb_u, bc_u, E, sgrid);
    bucket_scan<<<1, 1024, 0, stream>>>(bc_i, base_i, bcur_i, nb_i, bc_u, base_u, bcur_u, nb_u);
    binned_scatter2<<<2 * sgrid, 256, 0, stream>>>(
        eui_src, eui_dst, nb_i, bcur_i, pairs_i,
        eiu_src, eiu_dst, nb_u, bcur_u, pairs_u, E, sgrid);
    bucket_fill2<<<nb_i + nb_u, 256, 0, stream>>>(
        pairs_i, base_i, nb_i, NI, rp_i, col_ui,
        pairs_u, base_u, NU, rp_u, col_iu);

    // ---- converts (1 launch) ----
    {
        ConvArgs ca;
        auto seg = [&](int i, const float* in, u16* outp, size_t n) {
            ca.s[i].in = in; ca.s[i].out = outp; ca.s[i].n4 = (u32)(n / 4); ca.s[i].pad = 0;
        };
        seg(0, x_user, x_user_b, (size_t)NU * DU);
        seg(1, x_item, x_item_b, (size_t)NI * DI);
        seg(2, W2l_ui, W2l_ui_b, (size_t)HDIM * HDIM);
        seg(3, W2r_ui, W2r_ui_b, (size_t)HDIM * HDIM);
        seg(4, W2l_iu, W2l_iu_b, (size_t)HDIM * HDIM);
        seg(5, W2r_iu, W2r_iu_b, (size_t)HDIM * HDIM);
        seg(6, W1l_ui, W1l_ui_b, (size_t)HDIM * DU);
        seg(7, W1r_ui, W1r_ui_b, (size_t)HDIM * DI);
        seg(8, W1l_iu, W1l_iu_b, (size_t)HDIM * DI);
        seg(9, W1r_iu, W1r_iu_b, (size_t)HDIM * DU);
        u32 tot = 0;
        for (int i = 0; i < 10; i++) tot += ca.s[i].n4;
        ca.tot = tot;
        multi_convert<<<2048, 256, 0, stream>>>(ca);
    }

    // ---- layer 1 ----
    agg_mean<128><<<(NI + 3) / 4, 256, 0, stream>>>(x_user_b, rp_i, col_ui, A_i, NI);
    agg_mean<64> <<<(NU + 3) / 4, 256, 0, stream>>>(x_item_b, rp_u, col_iu, A_u, NU);
    {
        int gi = ((NI + 127) / 128) * 2;
        int gu = ((NU + 127) / 128) * 2;
        gemm_tile<128, 64, true, true><<<gi, 256, 0, stream>>>(
            A_i, x_item_b, W1l_ui_b, W1r_ui_b, b1_ui, nullptr, h_item_b, NI);
        gemm_tile<64, 128, true, true><<<gu, 256, 0, stream>>>(
            A_u, x_user_b, W1l_iu_b, W1r_iu_b, b1_iu, nullptr, h_user_b, NU);
    }

    // ---- layer 2 ----  (B_i overwrites x_user_b; B_u overwrites x_item/A_i/A_u: all dead)
    {
        int gi = (NI + 3) / 4;
        int gu = (NU + 3) / 4;
        agg_mean256_dual<<<gi + gu, 256, 0, stream>>>(
            h_user_b, rp_i, col_ui, B_i, NI, gi,
            h_item_b, rp_u, col_iu, B_u, NU);
    }
    {
        int gi = ((NI + 127) / 128) * 2;
        int gu = ((NU + 127) / 128) * 2;
        gemm_tile<256, 256, false, false><<<gi, 256, 0, stream>>>(
            B_i, h_item_b, W2l_ui_b, W2r_ui_b, b2_ui, out_item, nullptr, NI);
        gemm_tile<256, 256, false, false><<<gu, 256, 0, stream>>>(
            B_u, h_user_b, W2l_iu_b, W2r_iu_b, b2_iu, out_user, nullptr, NU);
    }
}